// Round 2
// baseline (1860.910 us; speedup 1.0000x reference)
//
#include <hip/hip_runtime.h>
#include <hip/hip_bf16.h>
#include <math.h>

typedef unsigned short u16;

#define Bz 64
#define Tt 4096
#define Cin 64
#define K1c 128
#define Hh 96
#define T2 1024
#define G4 384
#define NC 109

__device__ __forceinline__ float bf2f(u16 v) {
  union { unsigned int u; float f; } x; x.u = ((unsigned int)v) << 16; return x.f;
}
__device__ __forceinline__ u16 f2bf(float f) {
  union { unsigned int u; float f; } x; x.f = f;
  unsigned int u = x.u;
  unsigned int r = u + 0x7fff + ((u >> 16) & 1);
  return (u16)(r >> 16);
}

// ---------------- K0: weight transposes + BN folding ----------------
__global__ void k_prep(const float* __restrict__ w1, const float* __restrict__ cb1,
                       const float* __restrict__ g1, const float* __restrict__ b1,
                       const float* __restrict__ m1, const float* __restrict__ v1,
                       const float* __restrict__ w2, const float* __restrict__ cb2,
                       const float* __restrict__ g2, const float* __restrict__ b2,
                       const float* __restrict__ m2, const float* __restrict__ v2,
                       const float* __restrict__ wr, const float* __restrict__ cbr,
                       const float* __restrict__ gr, const float* __restrict__ br,
                       const float* __restrict__ mr, const float* __restrict__ vr,
                       const float* __restrict__ wx,
                       float* __restrict__ w1T, float* __restrict__ w2T,
                       float* __restrict__ wrT, float* __restrict__ wxT,
                       float* __restrict__ al1, float* __restrict__ be1,
                       float* __restrict__ al2, float* __restrict__ be2,
                       float* __restrict__ alr, float* __restrict__ ber)
{
  int tid = blockIdx.x * blockDim.x + threadIdx.x;
  int nth = gridDim.x * blockDim.x;
  // w1T[(i*7+k)*128 + o] = w1[o][i][k]
  for (int idx = tid; idx < 448 * 128; idx += nth) {
    int o = idx & 127, r = idx >> 7, i = r / 7, k = r % 7;
    w1T[idx] = w1[(o * 64 + i) * 7 + k];
  }
  // w2T[(i*3+k)*96 + o] = w2[o][i][k]
  for (int idx = tid; idx < 384 * 96; idx += nth) {
    int o = idx % 96, r = idx / 96, i = r / 3, k = r % 3;
    w2T[idx] = w2[(o * 128 + i) * 3 + k];
  }
  // wrT[i*96 + o] = wr[o][i]
  for (int idx = tid; idx < 128 * 96; idx += nth) {
    int o = idx % 96, i = idx / 96;
    wrT[idx] = wr[o * 128 + i];
  }
  // wxT[h*384 + g] = wx[g][h]
  for (int idx = tid; idx < 96 * 384; idx += nth) {
    int g = idx % 384, h = idx / 384;
    wxT[idx] = wx[g * 96 + h];
  }
  for (int o = tid; o < 128; o += nth) {
    float a = g1[o] / sqrtf(v1[o] + 1e-5f);
    al1[o] = a; be1[o] = b1[o] + (cb1[o] - m1[o]) * a;
  }
  for (int o = tid; o < 96; o += nth) {
    float a = g2[o] / sqrtf(v2[o] + 1e-5f);
    al2[o] = a; be2[o] = b2[o] + (cb2[o] - m2[o]) * a;
    float ar = gr[o] / sqrtf(vr[o] + 1e-5f);
    alr[o] = ar; ber[o] = br[o] + (cbr[o] - mr[o]) * ar;
  }
}

// ---------------- K1: conv1 (k=7,s=1,p=3) + bn1 + relu -> out1 bf16 [B][T][128] ----------------
__launch_bounds__(256)
__global__ void k_conv1(const float* __restrict__ x, const float* __restrict__ w1T,
                        const float* __restrict__ al1, const float* __restrict__ be1,
                        u16* __restrict__ out1)
{
  __shared__ __align__(16) float xsT[64 * 76];   // [i][row], rows 0..69 valid
  __shared__ __align__(16) float wbuf[56 * 128]; // K-slice of w1T
  int tid = threadIdx.x;
  int b = blockIdx.y;
  int t0 = blockIdx.x * 64;
  const float* xb = x + (size_t)b * Tt * Cin;
  for (int idx = tid; idx < 70 * 64; idx += 256) {
    int row = idx >> 6, col = idx & 63;
    int gt = t0 - 3 + row;
    float v = (gt >= 0 && gt < Tt) ? xb[(size_t)gt * 64 + col] : 0.f;
    xsT[col * 76 + row] = v;
  }
  int lane32 = tid & 31;
  int o4 = lane32 * 4;
  int trow = (tid >> 5) * 8;
  float acc[8][4];
#pragma unroll
  for (int m = 0; m < 8; m++)
#pragma unroll
    for (int j = 0; j < 4; j++) acc[m][j] = 0.f;

  for (int ib = 0; ib < 8; ib++) {
    __syncthreads();
    for (int idx = tid; idx < 56 * 128; idx += 256) wbuf[idx] = w1T[ib * 56 * 128 + idx];
    __syncthreads();
#pragma unroll
    for (int ii = 0; ii < 8; ii++) {
      int i = ib * 8 + ii;
      float ax[16];
      {
        const float4* xp = (const float4*)(xsT + i * 76 + trow);
        float4 q0 = xp[0], q1 = xp[1], q2 = xp[2], q3 = xp[3];
        ax[0] = q0.x; ax[1] = q0.y; ax[2] = q0.z; ax[3] = q0.w;
        ax[4] = q1.x; ax[5] = q1.y; ax[6] = q1.z; ax[7] = q1.w;
        ax[8] = q2.x; ax[9] = q2.y; ax[10] = q2.z; ax[11] = q2.w;
        ax[12] = q3.x; ax[13] = q3.y; ax[14] = q3.z; ax[15] = q3.w;
      }
#pragma unroll
      for (int k = 0; k < 7; k++) {
        float4 bw = ((const float4*)wbuf)[(ii * 7 + k) * 32 + lane32];
#pragma unroll
        for (int m = 0; m < 8; m++) {
          float a = ax[m + k];
          acc[m][0] += a * bw.x; acc[m][1] += a * bw.y;
          acc[m][2] += a * bw.z; acc[m][3] += a * bw.w;
        }
      }
    }
  }
  float4 A = *(const float4*)(al1 + o4);
  float4 Bt = *(const float4*)(be1 + o4);
  u16* ob = out1 + ((size_t)b * Tt + t0 + trow) * 128 + o4;
#pragma unroll
  for (int m = 0; m < 8; m++) {
    float v0 = fmaxf(acc[m][0] * A.x + Bt.x, 0.f);
    float v1 = fmaxf(acc[m][1] * A.y + Bt.y, 0.f);
    float v2 = fmaxf(acc[m][2] * A.z + Bt.z, 0.f);
    float v3 = fmaxf(acc[m][3] * A.w + Bt.w, 0.f);
    ushort4 s;
    s.x = f2bf(v0); s.y = f2bf(v1); s.z = f2bf(v2); s.w = f2bf(v3);
    *(ushort4*)(ob + (size_t)m * 128) = s;
  }
}

// ---------------- K2: conv2(k=3,s=4,p=1)+bn2+relu + res(k=1,s=4)+bnr, add -> seq f32 [B][1024][96] ----------------
__launch_bounds__(256)
__global__ void k_conv2(const u16* __restrict__ out1, const float* __restrict__ w2T,
                        const float* __restrict__ wrT,
                        const float* __restrict__ al2, const float* __restrict__ be2,
                        const float* __restrict__ alr, const float* __restrict__ ber,
                        float* __restrict__ seq)
{
  __shared__ __align__(16) u16 xs2[127 * 128];
  __shared__ float ws2[48 * 96];
  __shared__ float wsr[16 * 96];
  int tid = threadIdx.x;
  int b = blockIdx.y;
  int t20 = blockIdx.x * 32;
  int row0 = 4 * t20 - 1;
  const u16* ob = out1 + (size_t)b * Tt * 128;
  for (int idx4 = tid; idx4 < 127 * 32; idx4 += 256) {
    int row = idx4 >> 5, c4 = (idx4 & 31) * 4;
    int gr = row0 + row;
    ushort4 v;
    if (gr >= 0 && gr < Tt) v = *(const ushort4*)(ob + (size_t)gr * 128 + c4);
    else { v.x = 0; v.y = 0; v.z = 0; v.w = 0; }
    *(ushort4*)(xs2 + row * 128 + c4) = v;
  }
  int o3 = (tid & 31) * 3;
  int t4 = (tid >> 5) * 4;
  float acc[4][3], accr[4][3];
#pragma unroll
  for (int mt = 0; mt < 4; mt++)
#pragma unroll
    for (int j = 0; j < 3; j++) { acc[mt][j] = 0.f; accr[mt][j] = 0.f; }

  for (int ic = 0; ic < 8; ic++) {
    __syncthreads();
    int i0 = ic * 16;
    for (int idx = tid; idx < 48 * 96; idx += 256) ws2[idx] = w2T[i0 * 3 * 96 + idx];
    for (int idx = tid; idx < 16 * 96; idx += 256) wsr[idx] = wrT[i0 * 96 + idx];
    __syncthreads();
#pragma unroll
    for (int ii = 0; ii < 16; ii++) {
      int i = i0 + ii;
      float a[4][3];
#pragma unroll
      for (int mt = 0; mt < 4; mt++)
#pragma unroll
        for (int k = 0; k < 3; k++)
          a[mt][k] = bf2f(xs2[(4 * (t4 + mt) + k) * 128 + i]);
#pragma unroll
      for (int k = 0; k < 3; k++) {
        float w0 = ws2[(ii * 3 + k) * 96 + o3];
        float w1 = ws2[(ii * 3 + k) * 96 + o3 + 1];
        float w2v = ws2[(ii * 3 + k) * 96 + o3 + 2];
#pragma unroll
        for (int mt = 0; mt < 4; mt++) {
          acc[mt][0] += a[mt][k] * w0;
          acc[mt][1] += a[mt][k] * w1;
          acc[mt][2] += a[mt][k] * w2v;
        }
      }
      float r0 = wsr[ii * 96 + o3];
      float r1 = wsr[ii * 96 + o3 + 1];
      float r2 = wsr[ii * 96 + o3 + 2];
#pragma unroll
      for (int mt = 0; mt < 4; mt++) {
        accr[mt][0] += a[mt][1] * r0;
        accr[mt][1] += a[mt][1] * r1;
        accr[mt][2] += a[mt][1] * r2;
      }
    }
  }
  float A0 = al2[o3], A1 = al2[o3 + 1], A2 = al2[o3 + 2];
  float B0 = be2[o3], B1 = be2[o3 + 1], B2 = be2[o3 + 2];
  float Ar0 = alr[o3], Ar1 = alr[o3 + 1], Ar2 = alr[o3 + 2];
  float Br0 = ber[o3], Br1 = ber[o3 + 1], Br2 = ber[o3 + 2];
  float* sb = seq + ((size_t)b * T2 + t20 + t4) * 96 + o3;
#pragma unroll
  for (int mt = 0; mt < 4; mt++) {
    sb[(size_t)mt * 96 + 0] = fmaxf(acc[mt][0] * A0 + B0, 0.f) + accr[mt][0] * Ar0 + Br0;
    sb[(size_t)mt * 96 + 1] = fmaxf(acc[mt][1] * A1 + B1, 0.f) + accr[mt][1] * Ar1 + Br1;
    sb[(size_t)mt * 96 + 2] = fmaxf(acc[mt][2] * A2 + B2, 0.f) + accr[mt][2] * Ar2 + Br2;
  }
}

// ---------------- K3: pre = seq @ wx^T + bias -> [B][1024][384] f32 ----------------
__launch_bounds__(256)
__global__ void k_pre(const float* __restrict__ seq, const float* __restrict__ wxT,
                      const float* __restrict__ bias, float* __restrict__ pre)
{
  __shared__ float seqs[32 * 96];
  __shared__ __align__(16) float wxs[96 * 128];
  int tid = threadIdx.x;
  int b = blockIdx.z, nt = blockIdx.y, t20 = blockIdx.x * 32;
  int g0 = nt * 128;
  for (int idx = tid; idx < 32 * 96; idx += 256)
    seqs[idx] = seq[((size_t)b * T2 + t20) * 96 + idx];
  for (int idx = tid; idx < 96 * 128; idx += 256) {
    int h = idx >> 7, c = idx & 127;
    wxs[idx] = wxT[h * 384 + g0 + c];
  }
  __syncthreads();
  int lane32 = tid & 31, o4 = lane32 * 4, t4 = (tid >> 5) * 4;
  float acc[4][4];
#pragma unroll
  for (int mt = 0; mt < 4; mt++)
#pragma unroll
    for (int j = 0; j < 4; j++) acc[mt][j] = 0.f;
  for (int k = 0; k < 96; k++) {
    float4 bw = ((const float4*)wxs)[k * 32 + lane32];
    float a0 = seqs[(t4 + 0) * 96 + k];
    float a1 = seqs[(t4 + 1) * 96 + k];
    float a2 = seqs[(t4 + 2) * 96 + k];
    float a3 = seqs[(t4 + 3) * 96 + k];
    acc[0][0] += a0 * bw.x; acc[0][1] += a0 * bw.y; acc[0][2] += a0 * bw.z; acc[0][3] += a0 * bw.w;
    acc[1][0] += a1 * bw.x; acc[1][1] += a1 * bw.y; acc[1][2] += a1 * bw.z; acc[1][3] += a1 * bw.w;
    acc[2][0] += a2 * bw.x; acc[2][1] += a2 * bw.y; acc[2][2] += a2 * bw.z; acc[2][3] += a2 * bw.w;
    acc[3][0] += a3 * bw.x; acc[3][1] += a3 * bw.y; acc[3][2] += a3 * bw.z; acc[3][3] += a3 * bw.w;
  }
  float4 b4 = *(const float4*)(bias + g0 + o4);
  float* pb = pre + ((size_t)b * T2 + t20 + t4) * 384 + g0 + o4;
#pragma unroll
  for (int mt = 0; mt < 4; mt++) {
    float4 v;
    v.x = acc[mt][0] + b4.x; v.y = acc[mt][1] + b4.y;
    v.z = acc[mt][2] + b4.z; v.w = acc[mt][3] + b4.w;
    *(float4*)(pb + (size_t)mt * 384) = v;
  }
}

// ---------------- K4: sLSTM recurrence, one block per batch ----------------
// 768 threads = 12 waves. lane = chgrp*8 + j; channel ch = wave*8 + chgrp.
// 8 helper lanes per channel each cover a 12-wide slice of h for all 4 gates.
// Butterfly shfl_xor reduce -> every lane holds the 4 complete gate preacts;
// gate math replicated in-lane (state c,n,m per lane, identical in group).
// One barrier per step via ping-pong hbuf. pre prefetched 2 steps ahead.
__launch_bounds__(768)
__global__ void k_slstm(const float* __restrict__ pre, const float* __restrict__ wh,
                        float* __restrict__ hsum)
{
  __shared__ __align__(16) float hbuf[2][96];
  int tid = threadIdx.x;
  int b = blockIdx.x;
  int lane = tid & 63;
  int wv = tid >> 6;        // 0..11
  int chg = lane >> 3;      // 0..7
  int j = lane & 7;         // 0..7
  int ch = wv * 8 + chg;    // 0..95

  // weights: wg[q] = wh[(g*96+ch)*96 + j*12 + q], rows z,i,f,o
  float w0[12], w1[12], w2[12], w3[12];
  {
    const float* bgw = wh + ch * 96 + j * 12;
#pragma unroll
    for (int q3 = 0; q3 < 3; q3++) {
      float4 a0 = *(const float4*)(bgw + 0 * 9216 + q3 * 4);
      float4 a1 = *(const float4*)(bgw + 1 * 9216 + q3 * 4);
      float4 a2 = *(const float4*)(bgw + 2 * 9216 + q3 * 4);
      float4 a3 = *(const float4*)(bgw + 3 * 9216 + q3 * 4);
      w0[q3 * 4 + 0] = a0.x; w0[q3 * 4 + 1] = a0.y; w0[q3 * 4 + 2] = a0.z; w0[q3 * 4 + 3] = a0.w;
      w1[q3 * 4 + 0] = a1.x; w1[q3 * 4 + 1] = a1.y; w1[q3 * 4 + 2] = a1.z; w1[q3 * 4 + 3] = a1.w;
      w2[q3 * 4 + 0] = a2.x; w2[q3 * 4 + 1] = a2.y; w2[q3 * 4 + 2] = a2.z; w2[q3 * 4 + 3] = a2.w;
      w3[q3 * 4 + 0] = a3.x; w3[q3 * 4 + 1] = a3.y; w3[q3 * 4 + 2] = a3.z; w3[q3 * 4 + 3] = a3.w;
    }
  }

  float c = 0.f, n = 0.f, m = 0.f, hs = 0.f;
  if (tid < 96) { hbuf[0][tid] = 0.f; }
  __syncthreads();

  // px: lane j<4 carries pre[t][j*96+ch]; double prefetch (distance 2)
  const float* pxptr = pre + (size_t)b * T2 * G4 + j * 96 + ch;
  bool ldpx = (j < 4);
  float pxA = ldpx ? pxptr[0] : 0.f;
  float pxB = ldpx ? pxptr[G4] : 0.f;

  const float L2E = 1.44269504f;
  int p = 0;
  for (int t = 0; t < T2; t++) {
    // prefetch t+2 (issued first, consumed 2 iterations later)
    float pxN = 0.f;
    if (ldpx && t + 2 < T2) pxN = pxptr[(size_t)(t + 2) * G4];

    // read 12-wide h slice (LDS broadcast, conflict-free)
    const float4* hb = (const float4*)(&hbuf[p][j * 12]);
    float4 h0 = hb[0], h1 = hb[1], h2 = hb[2];
    float hv[12];
    hv[0] = h0.x; hv[1] = h0.y; hv[2] = h0.z; hv[3] = h0.w;
    hv[4] = h1.x; hv[5] = h1.y; hv[6] = h1.z; hv[7] = h1.w;
    hv[8] = h2.x; hv[9] = h2.y; hv[10] = h2.z; hv[11] = h2.w;

    float acc0 = (j == 0) ? pxA : 0.f;
    float acc1 = (j == 1) ? pxA : 0.f;
    float acc2 = (j == 2) ? pxA : 0.f;
    float acc3 = (j == 3) ? pxA : 0.f;
#pragma unroll
    for (int q = 0; q < 12; q++) {
      acc0 += hv[q] * w0[q];
      acc1 += hv[q] * w1[q];
      acc2 += hv[q] * w2[q];
      acc3 += hv[q] * w3[q];
    }
    // butterfly across the 8 helper lanes
#pragma unroll
    for (int d = 1; d < 8; d <<= 1) {
      acc0 += __shfl_xor(acc0, d);
      acc1 += __shfl_xor(acc1, d);
      acc2 += __shfl_xor(acc2, d);
      acc3 += __shfl_xor(acc3, d);
    }
    // gate math, replicated in all 8 lanes of the group
    float zp = acc0, ip = acc1, fp = acc2, op = acc3;
    float zc = fminf(fmaxf(zp, -30.f), 30.f);
    float ez = exp2f(zc * (2.f * L2E));
    float z = (ez - 1.f) / (ez + 1.f);
    float oc = fminf(fmaxf(op, -30.f), 30.f);
    float o = 1.f / (1.f + exp2f(-oc * L2E));
    float mn = fmaxf(fp + m, ip);
    float iv = exp2f((ip - mn) * L2E);
    float fv = exp2f((fp + m - mn) * L2E);
    c = fv * c + iv * z;
    n = fv * n + iv;
    m = mn;
    float h = o * (c / fmaxf(n, 1.f));
    hs += h;
    if (j == 0) hbuf[p ^ 1][ch] = h;
    pxA = pxB; pxB = pxN;
    __syncthreads();
    p ^= 1;
  }
  if (j == 0) hsum[b * 96 + ch] = hs * (1.f / 1024.f);
}

// ---------------- K5: head: mean-pooled -> fc1+relu -> fc2 ----------------
__launch_bounds__(128)
__global__ void k_head(const float* __restrict__ hsum, const float* __restrict__ fc1w,
                       const float* __restrict__ fc1b, const float* __restrict__ fc2w,
                       const float* __restrict__ fc2b, float* __restrict__ out)
{
  __shared__ float p[96];
  __shared__ float z1[128];
  int tid = threadIdx.x, b = blockIdx.x;
  if (tid < 96) p[tid] = hsum[b * 96 + tid];
  __syncthreads();
  {
    float a = fc1b[tid];
    const float* wr = fc1w + tid * 96;
    for (int h = 0; h < 96; h++) a += p[h] * wr[h];
    z1[tid] = fmaxf(a, 0.f);
  }
  __syncthreads();
  if (tid < NC) {
    float a = fc2b[tid];
    const float* wr = fc2w + tid * 128;
    for (int j = 0; j < 128; j++) a += z1[j] * wr[j];
    out[b * NC + tid] = a;
  }
}

extern "C" void kernel_launch(void* const* d_in, const int* in_sizes, int n_in,
                              void* d_out, int out_size, void* d_ws, size_t ws_size,
                              hipStream_t stream)
{
  const float* x    = (const float*)d_in[0];
  const float* w1   = (const float*)d_in[1];
  const float* cb1  = (const float*)d_in[2];
  const float* g1   = (const float*)d_in[3];
  const float* b1   = (const float*)d_in[4];
  const float* m1   = (const float*)d_in[5];
  const float* v1   = (const float*)d_in[6];
  const float* w2   = (const float*)d_in[7];
  const float* cb2  = (const float*)d_in[8];
  const float* g2   = (const float*)d_in[9];
  const float* b2   = (const float*)d_in[10];
  const float* m2   = (const float*)d_in[11];
  const float* v2   = (const float*)d_in[12];
  const float* wr   = (const float*)d_in[13];
  const float* cbr  = (const float*)d_in[14];
  const float* gr   = (const float*)d_in[15];
  const float* br   = (const float*)d_in[16];
  const float* mr   = (const float*)d_in[17];
  const float* vr   = (const float*)d_in[18];
  const float* wx   = (const float*)d_in[19];
  const float* wh   = (const float*)d_in[20];
  const float* sbia = (const float*)d_in[21];
  const float* fc1w = (const float*)d_in[22];
  const float* fc1b = (const float*)d_in[23];
  const float* fc2w = (const float*)d_in[24];
  const float* fc2b = (const float*)d_in[25];

  char* ws = (char*)d_ws;
  size_t off = 0;
  auto alloc = [&](size_t bytes) -> void* {
    void* p = (void*)(ws + off);
    off = (off + bytes + 255) & ~((size_t)255);
    return p;
  };
  u16*   out1 = (u16*)  alloc((size_t)Bz * Tt * K1c * 2);   // 67.1 MB
  float* seq  = (float*)alloc((size_t)Bz * T2 * Hh * 4);    // 25.2 MB
  float* pre  = (float*)alloc((size_t)Bz * T2 * G4 * 4);    // 100.7 MB
  float* w1T  = (float*)alloc(448 * 128 * 4);
  float* w2T  = (float*)alloc(384 * 96 * 4);
  float* wrT  = (float*)alloc(128 * 96 * 4);
  float* wxT  = (float*)alloc(96 * 384 * 4);
  float* al1  = (float*)alloc(128 * 4);
  float* be1  = (float*)alloc(128 * 4);
  float* al2  = (float*)alloc(96 * 4);
  float* be2  = (float*)alloc(96 * 4);
  float* alr  = (float*)alloc(96 * 4);
  float* ber  = (float*)alloc(96 * 4);
  float* hsum = (float*)alloc((size_t)Bz * Hh * 4);
  (void)ws_size; (void)in_sizes; (void)n_in; (void)out_size;

  k_prep<<<dim3(224), dim3(256), 0, stream>>>(
      w1, cb1, g1, b1, m1, v1, w2, cb2, g2, b2, m2, v2,
      wr, cbr, gr, br, mr, vr, wx,
      w1T, w2T, wrT, wxT, al1, be1, al2, be2, alr, ber);

  k_conv1<<<dim3(Tt / 64, Bz), dim3(256), 0, stream>>>(x, w1T, al1, be1, out1);

  k_conv2<<<dim3(T2 / 32, Bz), dim3(256), 0, stream>>>(out1, w2T, wrT, al2, be2, alr, ber, seq);

  k_pre<<<dim3(T2 / 32, 3, Bz), dim3(256), 0, stream>>>(seq, wxT, sbia, pre);

  k_slstm<<<dim3(Bz), dim3(768), 0, stream>>>(pre, wh, hsum);

  k_head<<<dim3(Bz), dim3(128), 0, stream>>>(hsum, fc1w, fc1b, fc2w, fc2b, (float*)d_out);
}

// Round 3
// 1275.334 us; speedup vs baseline: 1.4592x; 1.4592x over previous
//
#include <hip/hip_runtime.h>
#include <hip/hip_bf16.h>
#include <math.h>

typedef unsigned short u16;

#define Bz 64
#define Tt 4096
#define Cin 64
#define K1c 128
#define Hh 96
#define T2 1024
#define G4 384
#define NC 109

__device__ __forceinline__ float bf2f(u16 v) {
  union { unsigned int u; float f; } x; x.u = ((unsigned int)v) << 16; return x.f;
}
__device__ __forceinline__ u16 f2bf(float f) {
  union { unsigned int u; float f; } x; x.f = f;
  unsigned int u = x.u;
  unsigned int r = u + 0x7fff + ((u >> 16) & 1);
  return (u16)(r >> 16);
}
__device__ __forceinline__ float dpp_xor1(float x) {
  int r = __builtin_amdgcn_mov_dpp(__float_as_int(x), 0xB1, 0xF, 0xF, true);
  return __int_as_float(r);
}
__device__ __forceinline__ float dpp_xor2(float x) {
  int r = __builtin_amdgcn_mov_dpp(__float_as_int(x), 0x4E, 0xF, 0xF, true);
  return __int_as_float(r);
}

// ---------------- K0: weight transposes + BN folding ----------------
__global__ void k_prep(const float* __restrict__ w1, const float* __restrict__ cb1,
                       const float* __restrict__ g1, const float* __restrict__ b1,
                       const float* __restrict__ m1, const float* __restrict__ v1,
                       const float* __restrict__ w2, const float* __restrict__ cb2,
                       const float* __restrict__ g2, const float* __restrict__ b2,
                       const float* __restrict__ m2, const float* __restrict__ v2,
                       const float* __restrict__ wr, const float* __restrict__ cbr,
                       const float* __restrict__ gr, const float* __restrict__ br,
                       const float* __restrict__ mr, const float* __restrict__ vr,
                       const float* __restrict__ wx, const float* __restrict__ sbia,
                       float* __restrict__ w1T, float* __restrict__ w2T,
                       float* __restrict__ wrT, float* __restrict__ wxT,
                       float* __restrict__ bperm,
                       float* __restrict__ al1, float* __restrict__ be1,
                       float* __restrict__ al2, float* __restrict__ be2,
                       float* __restrict__ alr, float* __restrict__ ber)
{
  int tid = blockIdx.x * blockDim.x + threadIdx.x;
  int nth = gridDim.x * blockDim.x;
  // w1T[(i*7+k)*128 + o] = w1[o][i][k]
  for (int idx = tid; idx < 448 * 128; idx += nth) {
    int o = idx & 127, r = idx >> 7, i = r / 7, k = r % 7;
    w1T[idx] = w1[(o * 64 + i) * 7 + k];
  }
  // w2T[(i*3+k)*96 + o] = w2[o][i][k]
  for (int idx = tid; idx < 384 * 96; idx += nth) {
    int o = idx % 96, r = idx / 96, i = r / 3, k = r % 3;
    w2T[idx] = w2[(o * 128 + i) * 3 + k];
  }
  // wrT[i*96 + o] = wr[o][i]
  for (int idx = tid; idx < 128 * 96; idx += nth) {
    int o = idx % 96, i = idx / 96;
    wrT[idx] = wr[o * 128 + i];
  }
  // wxT[h*384 + (ch*4+g)] = wx[g*96+ch][h]  (permuted: ch-major gate packing)
  for (int idx = tid; idx < 96 * 384; idx += nth) {
    int c = idx % 384, h = idx / 384;
    int ch = c >> 2, g = c & 3;
    wxT[idx] = wx[((size_t)(g * 96 + ch)) * 96 + h];
  }
  // bperm[ch*4+g] = sbia[g*96+ch]
  for (int c = tid; c < 384; c += nth) {
    int ch = c >> 2, g = c & 3;
    bperm[c] = sbia[g * 96 + ch];
  }
  for (int o = tid; o < 128; o += nth) {
    float a = g1[o] / sqrtf(v1[o] + 1e-5f);
    al1[o] = a; be1[o] = b1[o] + (cb1[o] - m1[o]) * a;
  }
  for (int o = tid; o < 96; o += nth) {
    float a = g2[o] / sqrtf(v2[o] + 1e-5f);
    al2[o] = a; be2[o] = b2[o] + (cb2[o] - m2[o]) * a;
    float ar = gr[o] / sqrtf(vr[o] + 1e-5f);
    alr[o] = ar; ber[o] = br[o] + (cbr[o] - mr[o]) * ar;
  }
}

// ---------------- K1: conv1 (k=7,s=1,p=3) + bn1 + relu -> out1 bf16 [B][T][128] ----------------
__launch_bounds__(256)
__global__ void k_conv1(const float* __restrict__ x, const float* __restrict__ w1T,
                        const float* __restrict__ al1, const float* __restrict__ be1,
                        u16* __restrict__ out1)
{
  __shared__ __align__(16) float xsT[64 * 76];   // [i][row], rows 0..69 valid
  __shared__ __align__(16) float wbuf[56 * 128]; // K-slice of w1T
  int tid = threadIdx.x;
  int b = blockIdx.y;
  int t0 = blockIdx.x * 64;
  const float* xb = x + (size_t)b * Tt * Cin;
  for (int idx = tid; idx < 70 * 64; idx += 256) {
    int row = idx >> 6, col = idx & 63;
    int gt = t0 - 3 + row;
    float v = (gt >= 0 && gt < Tt) ? xb[(size_t)gt * 64 + col] : 0.f;
    xsT[col * 76 + row] = v;
  }
  int lane32 = tid & 31;
  int o4 = lane32 * 4;
  int trow = (tid >> 5) * 8;
  float acc[8][4];
#pragma unroll
  for (int m = 0; m < 8; m++)
#pragma unroll
    for (int j = 0; j < 4; j++) acc[m][j] = 0.f;

  for (int ib = 0; ib < 8; ib++) {
    __syncthreads();
    for (int idx = tid; idx < 56 * 128; idx += 256) wbuf[idx] = w1T[ib * 56 * 128 + idx];
    __syncthreads();
#pragma unroll
    for (int ii = 0; ii < 8; ii++) {
      int i = ib * 8 + ii;
      float ax[16];
      {
        const float4* xp = (const float4*)(xsT + i * 76 + trow);
        float4 q0 = xp[0], q1 = xp[1], q2 = xp[2], q3 = xp[3];
        ax[0] = q0.x; ax[1] = q0.y; ax[2] = q0.z; ax[3] = q0.w;
        ax[4] = q1.x; ax[5] = q1.y; ax[6] = q1.z; ax[7] = q1.w;
        ax[8] = q2.x; ax[9] = q2.y; ax[10] = q2.z; ax[11] = q2.w;
        ax[12] = q3.x; ax[13] = q3.y; ax[14] = q3.z; ax[15] = q3.w;
      }
#pragma unroll
      for (int k = 0; k < 7; k++) {
        float4 bw = ((const float4*)wbuf)[(ii * 7 + k) * 32 + lane32];
#pragma unroll
        for (int m = 0; m < 8; m++) {
          float a = ax[m + k];
          acc[m][0] += a * bw.x; acc[m][1] += a * bw.y;
          acc[m][2] += a * bw.z; acc[m][3] += a * bw.w;
        }
      }
    }
  }
  float4 A = *(const float4*)(al1 + o4);
  float4 Bt = *(const float4*)(be1 + o4);
  u16* ob = out1 + ((size_t)b * Tt + t0 + trow) * 128 + o4;
#pragma unroll
  for (int m = 0; m < 8; m++) {
    float v0 = fmaxf(acc[m][0] * A.x + Bt.x, 0.f);
    float v1 = fmaxf(acc[m][1] * A.y + Bt.y, 0.f);
    float v2 = fmaxf(acc[m][2] * A.z + Bt.z, 0.f);
    float v3 = fmaxf(acc[m][3] * A.w + Bt.w, 0.f);
    ushort4 s;
    s.x = f2bf(v0); s.y = f2bf(v1); s.z = f2bf(v2); s.w = f2bf(v3);
    *(ushort4*)(ob + (size_t)m * 128) = s;
  }
}

// ---------------- K2: conv2(k=3,s=4,p=1)+bn2+relu + res(k=1,s=4)+bnr, add -> seq f32 [B][1024][96] ----------------
__launch_bounds__(256)
__global__ void k_conv2(const u16* __restrict__ out1, const float* __restrict__ w2T,
                        const float* __restrict__ wrT,
                        const float* __restrict__ al2, const float* __restrict__ be2,
                        const float* __restrict__ alr, const float* __restrict__ ber,
                        float* __restrict__ seq)
{
  __shared__ __align__(16) u16 xs2[127 * 128];
  __shared__ float ws2[48 * 96];
  __shared__ float wsr[16 * 96];
  int tid = threadIdx.x;
  int b = blockIdx.y;
  int t20 = blockIdx.x * 32;
  int row0 = 4 * t20 - 1;
  const u16* ob = out1 + (size_t)b * Tt * 128;
  for (int idx4 = tid; idx4 < 127 * 32; idx4 += 256) {
    int row = idx4 >> 5, c4 = (idx4 & 31) * 4;
    int gr = row0 + row;
    ushort4 v;
    if (gr >= 0 && gr < Tt) v = *(const ushort4*)(ob + (size_t)gr * 128 + c4);
    else { v.x = 0; v.y = 0; v.z = 0; v.w = 0; }
    *(ushort4*)(xs2 + row * 128 + c4) = v;
  }
  int o3 = (tid & 31) * 3;
  int t4 = (tid >> 5) * 4;
  float acc[4][3], accr[4][3];
#pragma unroll
  for (int mt = 0; mt < 4; mt++)
#pragma unroll
    for (int j = 0; j < 3; j++) { acc[mt][j] = 0.f; accr[mt][j] = 0.f; }

  for (int ic = 0; ic < 8; ic++) {
    __syncthreads();
    int i0 = ic * 16;
    for (int idx = tid; idx < 48 * 96; idx += 256) ws2[idx] = w2T[i0 * 3 * 96 + idx];
    for (int idx = tid; idx < 16 * 96; idx += 256) wsr[idx] = wrT[i0 * 96 + idx];
    __syncthreads();
#pragma unroll
    for (int ii = 0; ii < 16; ii++) {
      int i = i0 + ii;
      float a[4][3];
#pragma unroll
      for (int mt = 0; mt < 4; mt++)
#pragma unroll
        for (int k = 0; k < 3; k++)
          a[mt][k] = bf2f(xs2[(4 * (t4 + mt) + k) * 128 + i]);
#pragma unroll
      for (int k = 0; k < 3; k++) {
        float w0 = ws2[(ii * 3 + k) * 96 + o3];
        float w1 = ws2[(ii * 3 + k) * 96 + o3 + 1];
        float w2v = ws2[(ii * 3 + k) * 96 + o3 + 2];
#pragma unroll
        for (int mt = 0; mt < 4; mt++) {
          acc[mt][0] += a[mt][k] * w0;
          acc[mt][1] += a[mt][k] * w1;
          acc[mt][2] += a[mt][k] * w2v;
        }
      }
      float r0 = wsr[ii * 96 + o3];
      float r1 = wsr[ii * 96 + o3 + 1];
      float r2 = wsr[ii * 96 + o3 + 2];
#pragma unroll
      for (int mt = 0; mt < 4; mt++) {
        accr[mt][0] += a[mt][1] * r0;
        accr[mt][1] += a[mt][1] * r1;
        accr[mt][2] += a[mt][1] * r2;
      }
    }
  }
  float A0 = al2[o3], A1 = al2[o3 + 1], A2 = al2[o3 + 2];
  float B0 = be2[o3], B1 = be2[o3 + 1], B2 = be2[o3 + 2];
  float Ar0 = alr[o3], Ar1 = alr[o3 + 1], Ar2 = alr[o3 + 2];
  float Br0 = ber[o3], Br1 = ber[o3 + 1], Br2 = ber[o3 + 2];
  float* sb = seq + ((size_t)b * T2 + t20 + t4) * 96 + o3;
#pragma unroll
  for (int mt = 0; mt < 4; mt++) {
    sb[(size_t)mt * 96 + 0] = fmaxf(acc[mt][0] * A0 + B0, 0.f) + accr[mt][0] * Ar0 + Br0;
    sb[(size_t)mt * 96 + 1] = fmaxf(acc[mt][1] * A1 + B1, 0.f) + accr[mt][1] * Ar1 + Br1;
    sb[(size_t)mt * 96 + 2] = fmaxf(acc[mt][2] * A2 + B2, 0.f) + accr[mt][2] * Ar2 + Br2;
  }
}

// ---------------- K3: pre = seq @ wxT + bias -> [B][1024][384] f32 (permuted: idx = ch*4+g) ----------------
__launch_bounds__(256)
__global__ void k_pre(const float* __restrict__ seq, const float* __restrict__ wxT,
                      const float* __restrict__ bias, float* __restrict__ pre)
{
  __shared__ float seqs[32 * 96];
  __shared__ __align__(16) float wxs[96 * 128];
  int tid = threadIdx.x;
  int b = blockIdx.z, nt = blockIdx.y, t20 = blockIdx.x * 32;
  int g0 = nt * 128;
  for (int idx = tid; idx < 32 * 96; idx += 256)
    seqs[idx] = seq[((size_t)b * T2 + t20) * 96 + idx];
  for (int idx = tid; idx < 96 * 128; idx += 256) {
    int h = idx >> 7, c = idx & 127;
    wxs[idx] = wxT[h * 384 + g0 + c];
  }
  __syncthreads();
  int lane32 = tid & 31, o4 = lane32 * 4, t4 = (tid >> 5) * 4;
  float acc[4][4];
#pragma unroll
  for (int mt = 0; mt < 4; mt++)
#pragma unroll
    for (int j = 0; j < 4; j++) acc[mt][j] = 0.f;
  for (int k = 0; k < 96; k++) {
    float4 bw = ((const float4*)wxs)[k * 32 + lane32];
    float a0 = seqs[(t4 + 0) * 96 + k];
    float a1 = seqs[(t4 + 1) * 96 + k];
    float a2 = seqs[(t4 + 2) * 96 + k];
    float a3 = seqs[(t4 + 3) * 96 + k];
    acc[0][0] += a0 * bw.x; acc[0][1] += a0 * bw.y; acc[0][2] += a0 * bw.z; acc[0][3] += a0 * bw.w;
    acc[1][0] += a1 * bw.x; acc[1][1] += a1 * bw.y; acc[1][2] += a1 * bw.z; acc[1][3] += a1 * bw.w;
    acc[2][0] += a2 * bw.x; acc[2][1] += a2 * bw.y; acc[2][2] += a2 * bw.z; acc[2][3] += a2 * bw.w;
    acc[3][0] += a3 * bw.x; acc[3][1] += a3 * bw.y; acc[3][2] += a3 * bw.z; acc[3][3] += a3 * bw.w;
  }
  float4 b4 = *(const float4*)(bias + g0 + o4);
  float* pb = pre + ((size_t)b * T2 + t20 + t4) * 384 + g0 + o4;
#pragma unroll
  for (int mt = 0; mt < 4; mt++) {
    float4 v;
    v.x = acc[mt][0] + b4.x; v.y = acc[mt][1] + b4.y;
    v.z = acc[mt][2] + b4.z; v.w = acc[mt][3] + b4.w;
    *(float4*)(pb + (size_t)mt * 384) = v;
  }
}

// ---------------- K4: sLSTM recurrence v3 ----------------
// 256 threads = 4 waves (1/SIMD), one block per batch.
// Wave w owns channels [24w, 24w+24). Lane (q=lane>>2, j=lane&3):
//   6 local rows lr=6q..6q+5 (lr = ch_local*4 + gate), 24-wide h-slice j*24.
//   Weights in 144 VGPRs. Quad reduce via DPP quad_perm (VALU pipe, no DS).
//   Preact write->gather is intra-wave (LDS FIFO), gate math in lanes 0..23,
//   one s_barrier per step (h publish, ping-pong hbuf).
// pre is read as [t][ch*4+g] float4 per gate lane, prefetch distance 2.
__launch_bounds__(256, 1)
__global__ void k_slstm(const float* __restrict__ pre, const float* __restrict__ wh,
                        float* __restrict__ hsum)
{
  __shared__ __align__(16) float hbuf[2][96];
  __shared__ __align__(16) float pwbuf[4][96];
  int tid = threadIdx.x;
  int b = blockIdx.x;
  int w = tid >> 6;
  int lane = tid & 63;
  int q = lane >> 2, j = lane & 3;

  // weights: wq[a][kq] = wh[(g*96+ch)*96 + j*24 + kq*4 ...]
  float4 wq[6][6];
#pragma unroll
  for (int a = 0; a < 6; a++) {
    int lr = 6 * q + a;
    int chl = lr >> 2, g = lr & 3;
    int ch = w * 24 + chl;
    const float4* wrow = (const float4*)(wh + ((size_t)(g * 96 + ch)) * 96 + j * 24);
#pragma unroll
    for (int kq = 0; kq < 6; kq++) wq[a][kq] = wrow[kq];
  }

  bool gl = (lane < 24);
  float c = 0.f, n = 0.f, m = 0.f, hs = 0.f;
  if (tid < 96) hbuf[0][tid] = 0.f;
  __syncthreads();

  // px prefetch (gate lanes): float4 (z,i,f,o) for ch = w*24+lane
  const float4* pxp = (const float4*)(pre + (size_t)b * T2 * G4) + (w * 24 + lane);
  float4 pxA = make_float4(0, 0, 0, 0), pxB = pxA;
  if (gl) { pxA = pxp[0]; pxB = pxp[96]; }

  const float L2E = 1.44269504f;
  int p = 0;
  for (int t = 0; t < T2; t++) {
    float4 pxN = make_float4(0, 0, 0, 0);
    if (gl) {
      int tn = t + 2 < T2 ? t + 2 : T2 - 1;
      pxN = pxp[(size_t)tn * 96];
    }
    // h slice (6 x ds_read_b128, 4 distinct addrs/wave, conflict-free)
    float4 hq[6];
#pragma unroll
    for (int kq = 0; kq < 6; kq++) hq[kq] = *(const float4*)(&hbuf[p][j * 24 + kq * 4]);

    float acc[6];
#pragma unroll
    for (int a = 0; a < 6; a++) {
      float s = 0.f;
#pragma unroll
      for (int kq = 0; kq < 6; kq++) {
        s += hq[kq].x * wq[a][kq].x;
        s += hq[kq].y * wq[a][kq].y;
        s += hq[kq].z * wq[a][kq].z;
        s += hq[kq].w * wq[a][kq].w;
      }
      // quad reduce over j (VALU-only DPP)
      s += dpp_xor1(s);
      s += dpp_xor2(s);
      acc[a] = s;
    }
    // intra-wave preact publish (j==0 lanes)
    if (j == 0) {
      *(float2*)(&pwbuf[w][6 * q + 0]) = make_float2(acc[0], acc[1]);
      *(float2*)(&pwbuf[w][6 * q + 2]) = make_float2(acc[2], acc[3]);
      *(float2*)(&pwbuf[w][6 * q + 4]) = make_float2(acc[4], acc[5]);
    }
    asm volatile("" ::: "memory");  // keep DS order (HW: per-wave LDS FIFO)
    if (gl) {
      float4 pa = *(const float4*)(&pwbuf[w][lane * 4]);
      float zp = pa.x + pxA.x, ip = pa.y + pxA.y;
      float fp = pa.z + pxA.z, op = pa.w + pxA.w;
      float zc = fminf(fmaxf(zp, -30.f), 30.f);
      float ez = exp2f(zc * (2.f * L2E));
      float z = 1.f - 2.f * __builtin_amdgcn_rcpf(ez + 1.f);
      float oc = fminf(fmaxf(op, -30.f), 30.f);
      float o = __builtin_amdgcn_rcpf(1.f + exp2f(-oc * L2E));
      float mn = fmaxf(fp + m, ip);
      float iv = exp2f((ip - mn) * L2E);
      float fv = exp2f((fp + m - mn) * L2E);
      c = fv * c + iv * z;
      n = fv * n + iv;
      m = mn;
      float h = o * c * __builtin_amdgcn_rcpf(fmaxf(n, 1.f));
      hs += h;
      hbuf[p ^ 1][w * 24 + lane] = h;
    }
    pxA = pxB; pxB = pxN;
    __syncthreads();
    p ^= 1;
  }
  if (gl) hsum[b * 96 + w * 24 + lane] = hs * (1.f / 1024.f);
}

// ---------------- K5: head: mean-pooled -> fc1+relu -> fc2 ----------------
__launch_bounds__(128)
__global__ void k_head(const float* __restrict__ hsum, const float* __restrict__ fc1w,
                       const float* __restrict__ fc1b, const float* __restrict__ fc2w,
                       const float* __restrict__ fc2b, float* __restrict__ out)
{
  __shared__ float p[96];
  __shared__ float z1[128];
  int tid = threadIdx.x, b = blockIdx.x;
  if (tid < 96) p[tid] = hsum[b * 96 + tid];
  __syncthreads();
  {
    float a = fc1b[tid];
    const float* wr = fc1w + tid * 96;
    for (int h = 0; h < 96; h++) a += p[h] * wr[h];
    z1[tid] = fmaxf(a, 0.f);
  }
  __syncthreads();
  if (tid < NC) {
    float a = fc2b[tid];
    const float* wr = fc2w + tid * 128;
    for (int j = 0; j < 128; j++) a += z1[j] * wr[j];
    out[b * NC + tid] = a;
  }
}

extern "C" void kernel_launch(void* const* d_in, const int* in_sizes, int n_in,
                              void* d_out, int out_size, void* d_ws, size_t ws_size,
                              hipStream_t stream)
{
  const float* x    = (const float*)d_in[0];
  const float* w1   = (const float*)d_in[1];
  const float* cb1  = (const float*)d_in[2];
  const float* g1   = (const float*)d_in[3];
  const float* b1   = (const float*)d_in[4];
  const float* m1   = (const float*)d_in[5];
  const float* v1   = (const float*)d_in[6];
  const float* w2   = (const float*)d_in[7];
  const float* cb2  = (const float*)d_in[8];
  const float* g2   = (const float*)d_in[9];
  const float* b2   = (const float*)d_in[10];
  const float* m2   = (const float*)d_in[11];
  const float* v2   = (const float*)d_in[12];
  const float* wr   = (const float*)d_in[13];
  const float* cbr  = (const float*)d_in[14];
  const float* gr   = (const float*)d_in[15];
  const float* br   = (const float*)d_in[16];
  const float* mr   = (const float*)d_in[17];
  const float* vr   = (const float*)d_in[18];
  const float* wx   = (const float*)d_in[19];
  const float* wh   = (const float*)d_in[20];
  const float* sbia = (const float*)d_in[21];
  const float* fc1w = (const float*)d_in[22];
  const float* fc1b = (const float*)d_in[23];
  const float* fc2w = (const float*)d_in[24];
  const float* fc2b = (const float*)d_in[25];

  char* ws = (char*)d_ws;
  size_t off = 0;
  auto alloc = [&](size_t bytes) -> void* {
    void* p = (void*)(ws + off);
    off = (off + bytes + 255) & ~((size_t)255);
    return p;
  };
  u16*   out1 = (u16*)  alloc((size_t)Bz * Tt * K1c * 2);   // 67.1 MB
  float* seq  = (float*)alloc((size_t)Bz * T2 * Hh * 4);    // 25.2 MB
  float* pre  = (float*)alloc((size_t)Bz * T2 * G4 * 4);    // 100.7 MB
  float* w1T  = (float*)alloc(448 * 128 * 4);
  float* w2T  = (float*)alloc(384 * 96 * 4);
  float* wrT  = (float*)alloc(128 * 96 * 4);
  float* wxT  = (float*)alloc(96 * 384 * 4);
  float* bperm= (float*)alloc(384 * 4);
  float* al1  = (float*)alloc(128 * 4);
  float* be1  = (float*)alloc(128 * 4);
  float* al2  = (float*)alloc(96 * 4);
  float* be2  = (float*)alloc(96 * 4);
  float* alr  = (float*)alloc(96 * 4);
  float* ber  = (float*)alloc(96 * 4);
  float* hsum = (float*)alloc((size_t)Bz * Hh * 4);
  (void)ws_size; (void)in_sizes; (void)n_in; (void)out_size;

  k_prep<<<dim3(224), dim3(256), 0, stream>>>(
      w1, cb1, g1, b1, m1, v1, w2, cb2, g2, b2, m2, v2,
      wr, cbr, gr, br, mr, vr, wx, sbia,
      w1T, w2T, wrT, wxT, bperm, al1, be1, al2, be2, alr, ber);

  k_conv1<<<dim3(Tt / 64, Bz), dim3(256), 0, stream>>>(x, w1T, al1, be1, out1);

  k_conv2<<<dim3(T2 / 32, Bz), dim3(256), 0, stream>>>(out1, w2T, wrT, al2, be2, alr, ber, seq);

  k_pre<<<dim3(T2 / 32, 3, Bz), dim3(256), 0, stream>>>(seq, wxT, bperm, pre);

  k_slstm<<<dim3(Bz), dim3(256), 0, stream>>>(pre, wh, hsum);

  k_head<<<dim3(Bz), dim3(128), 0, stream>>>(hsum, fc1w, fc1b, fc2w, fc2b, (float*)d_out);
}

// Round 4
// 1008.210 us; speedup vs baseline: 1.8458x; 1.2649x over previous
//
#include <hip/hip_runtime.h>
#include <hip/hip_bf16.h>
#include <math.h>

typedef unsigned short u16;
typedef short bf16x8 __attribute__((ext_vector_type(8)));
typedef float f32x4 __attribute__((ext_vector_type(4)));

#define Bz 64
#define Tt 4096
#define Cin 64
#define K1c 128
#define Hh 96
#define T2 1024
#define G4 384
#define NC 109

#define MFMA16(a, b, c) __builtin_amdgcn_mfma_f32_16x16x32_bf16(a, b, c, 0, 0, 0)

__device__ __forceinline__ float bf2f(u16 v) {
  union { unsigned int u; float f; } x; x.u = ((unsigned int)v) << 16; return x.f;
}
__device__ __forceinline__ u16 f2bf(float f) {
  union { unsigned int u; float f; } x; x.f = f;
  unsigned int u = x.u;
  unsigned int r = u + 0x7fff + ((u >> 16) & 1);
  return (u16)(r >> 16);
}
__device__ __forceinline__ float dpp_xor1(float x) {
  int r = __builtin_amdgcn_mov_dpp(__float_as_int(x), 0xB1, 0xF, 0xF, true);
  return __int_as_float(r);
}
__device__ __forceinline__ float dpp_xor2(float x) {
  int r = __builtin_amdgcn_mov_dpp(__float_as_int(x), 0x4E, 0xF, 0xF, true);
  return __int_as_float(r);
}

// ---------------- K0: weight transposes + BN folding ----------------
__global__ void k_prep(const float* __restrict__ w1, const float* __restrict__ cb1,
                       const float* __restrict__ g1, const float* __restrict__ b1,
                       const float* __restrict__ m1, const float* __restrict__ v1,
                       const float* __restrict__ w2, const float* __restrict__ cb2,
                       const float* __restrict__ g2, const float* __restrict__ b2,
                       const float* __restrict__ m2, const float* __restrict__ v2,
                       const float* __restrict__ wr, const float* __restrict__ cbr,
                       const float* __restrict__ gr, const float* __restrict__ br,
                       const float* __restrict__ mr, const float* __restrict__ vr,
                       const float* __restrict__ wx, const float* __restrict__ sbia,
                       u16* __restrict__ w1b, float* __restrict__ w2T,
                       float* __restrict__ wrT, float* __restrict__ wxT,
                       float* __restrict__ bperm,
                       float* __restrict__ al1, float* __restrict__ be1,
                       float* __restrict__ al2, float* __restrict__ be2,
                       float* __restrict__ alr, float* __restrict__ ber)
{
  int tid = blockIdx.x * blockDim.x + threadIdx.x;
  int nth = gridDim.x * blockDim.x;
  // w1b[o*448 + kt*64 + c] = bf16(w1[o][c][kt])
  for (int idx = tid; idx < 128 * 448; idx += nth) {
    int o = idx / 448, k = idx % 448;
    int kt = k >> 6, c = k & 63;
    w1b[idx] = f2bf(w1[(o * 64 + c) * 7 + kt]);
  }
  // w2T[(i*3+k)*96 + o] = w2[o][i][k]
  for (int idx = tid; idx < 384 * 96; idx += nth) {
    int o = idx % 96, r = idx / 96, i = r / 3, k = r % 3;
    w2T[idx] = w2[(o * 128 + i) * 3 + k];
  }
  // wrT[i*96 + o] = wr[o][i]
  for (int idx = tid; idx < 128 * 96; idx += nth) {
    int o = idx % 96, i = idx / 96;
    wrT[idx] = wr[o * 128 + i];
  }
  // wxT[h*384 + (ch*4+g)] = wx[g*96+ch][h]  (permuted: ch-major gate packing)
  for (int idx = tid; idx < 96 * 384; idx += nth) {
    int c = idx % 384, h = idx / 384;
    int ch = c >> 2, g = c & 3;
    wxT[idx] = wx[((size_t)(g * 96 + ch)) * 96 + h];
  }
  // bperm[ch*4+g] = sbia[g*96+ch]
  for (int c = tid; c < 384; c += nth) {
    int ch = c >> 2, g = c & 3;
    bperm[c] = sbia[g * 96 + ch];
  }
  for (int o = tid; o < 128; o += nth) {
    float a = g1[o] / sqrtf(v1[o] + 1e-5f);
    al1[o] = a; be1[o] = b1[o] + (cb1[o] - m1[o]) * a;
  }
  for (int o = tid; o < 96; o += nth) {
    float a = g2[o] / sqrtf(v2[o] + 1e-5f);
    al2[o] = a; be2[o] = b2[o] + (cb2[o] - m2[o]) * a;
    float ar = gr[o] / sqrtf(vr[o] + 1e-5f);
    alr[o] = ar; ber[o] = br[o] + (cbr[o] - mr[o]) * ar;
  }
}

// ---------------- K1: conv1 MFMA implicit GEMM ----------------
// M = B*T (tile 128 t-rows), N = 128 out-ch, K = 448 (kt*64 + c).
// 4 waves in 2x2; per-wave 64x64 output = 4x4 mfma_f32_16x16x32_bf16 frags.
// x tile staged once in LDS as bf16 [134][72]; no barriers in K-loop.
// Weights (bf16, 114KB) read per-fragment from global (L2-resident).
__launch_bounds__(256, 2)
__global__ void k_conv1(const float* __restrict__ x, const u16* __restrict__ w1b,
                        const float* __restrict__ al1, const float* __restrict__ be1,
                        u16* __restrict__ out1)
{
  __shared__ __align__(16) u16 xs[134 * 72];
  int tid = threadIdx.x;
  int b = blockIdx.y;
  int t0 = blockIdx.x * 128;
  const float* xb = x + (size_t)b * Tt * Cin;

  // stage x[t0-3 .. t0+130] x 64ch as bf16
  for (int idx = tid; idx < 134 * 16; idx += 256) {
    int row = idx >> 4, c4 = (idx & 15) << 2;
    int gt = t0 - 3 + row;
    float4 v = make_float4(0.f, 0.f, 0.f, 0.f);
    if (gt >= 0 && gt < Tt) v = *(const float4*)(xb + (size_t)gt * 64 + c4);
    ushort4 s;
    s.x = f2bf(v.x); s.y = f2bf(v.y); s.z = f2bf(v.z); s.w = f2bf(v.w);
    *(ushort4*)(xs + row * 72 + c4) = s;
  }
  __syncthreads();

  int l = tid & 63;
  int wid = tid >> 6;
  int wm = wid >> 1, wn = wid & 1;
  int lr = l & 15, g = l >> 4;

  f32x4 acc[4][4];
#pragma unroll
  for (int i = 0; i < 4; i++)
#pragma unroll
    for (int j = 0; j < 4; j++) acc[i][j] = (f32x4){0.f, 0.f, 0.f, 0.f};

  const u16* wbase = w1b + (size_t)(wn * 64 + lr) * 448;

  for (int s = 0; s < 14; ++s) {
    int kt = s >> 1;
    int cofs = ((s & 1) << 5) + (g << 3);
    const u16* xrow = xs + (wm * 64 + lr + kt) * 72 + cofs;
    bf16x8 a0 = *(const bf16x8*)(xrow);
    bf16x8 a1 = *(const bf16x8*)(xrow + 16 * 72);
    bf16x8 a2 = *(const bf16x8*)(xrow + 32 * 72);
    bf16x8 a3 = *(const bf16x8*)(xrow + 48 * 72);
    int ko = (s << 5) + (g << 3);
    bf16x8 b0 = *(const bf16x8*)(wbase + ko);
    bf16x8 b1 = *(const bf16x8*)(wbase + 16 * 448 + ko);
    bf16x8 b2 = *(const bf16x8*)(wbase + 32 * 448 + ko);
    bf16x8 b3 = *(const bf16x8*)(wbase + 48 * 448 + ko);
    acc[0][0] = MFMA16(a0, b0, acc[0][0]);
    acc[0][1] = MFMA16(a0, b1, acc[0][1]);
    acc[0][2] = MFMA16(a0, b2, acc[0][2]);
    acc[0][3] = MFMA16(a0, b3, acc[0][3]);
    acc[1][0] = MFMA16(a1, b0, acc[1][0]);
    acc[1][1] = MFMA16(a1, b1, acc[1][1]);
    acc[1][2] = MFMA16(a1, b2, acc[1][2]);
    acc[1][3] = MFMA16(a1, b3, acc[1][3]);
    acc[2][0] = MFMA16(a2, b0, acc[2][0]);
    acc[2][1] = MFMA16(a2, b1, acc[2][1]);
    acc[2][2] = MFMA16(a2, b2, acc[2][2]);
    acc[2][3] = MFMA16(a2, b3, acc[2][3]);
    acc[3][0] = MFMA16(a3, b0, acc[3][0]);
    acc[3][1] = MFMA16(a3, b1, acc[3][1]);
    acc[3][2] = MFMA16(a3, b2, acc[3][2]);
    acc[3][3] = MFMA16(a3, b3, acc[3][3]);
  }

  // epilogue: C/D layout col=lane&15, row=(lane>>4)*4+reg
  int colb = wn * 64 + lr;
  int rowb = t0 + wm * 64 + (l >> 4) * 4;
#pragma unroll
  for (int nf = 0; nf < 4; nf++) {
    int col = colb + nf * 16;
    float A = al1[col], Bt = be1[col];
#pragma unroll
    for (int mf = 0; mf < 4; mf++) {
      int row = rowb + mf * 16;
#pragma unroll
      for (int r = 0; r < 4; r++) {
        float v = acc[mf][nf][r];
        v = fmaxf(v * A + Bt, 0.f);
        out1[((size_t)b * Tt + row + r) * 128 + col] = f2bf(v);
      }
    }
  }
}

// ---------------- K2: conv2(k=3,s=4,p=1)+bn2+relu + res(k=1,s=4)+bnr, add -> seq f32 [B][1024][96] ----------------
__launch_bounds__(256)
__global__ void k_conv2(const u16* __restrict__ out1, const float* __restrict__ w2T,
                        const float* __restrict__ wrT,
                        const float* __restrict__ al2, const float* __restrict__ be2,
                        const float* __restrict__ alr, const float* __restrict__ ber,
                        float* __restrict__ seq)
{
  __shared__ __align__(16) u16 xs2[127 * 128];
  __shared__ float ws2[48 * 96];
  __shared__ float wsr[16 * 96];
  int tid = threadIdx.x;
  int b = blockIdx.y;
  int t20 = blockIdx.x * 32;
  int row0 = 4 * t20 - 1;
  const u16* ob = out1 + (size_t)b * Tt * 128;
  for (int idx4 = tid; idx4 < 127 * 32; idx4 += 256) {
    int row = idx4 >> 5, c4 = (idx4 & 31) * 4;
    int gr = row0 + row;
    ushort4 v;
    if (gr >= 0 && gr < Tt) v = *(const ushort4*)(ob + (size_t)gr * 128 + c4);
    else { v.x = 0; v.y = 0; v.z = 0; v.w = 0; }
    *(ushort4*)(xs2 + row * 128 + c4) = v;
  }
  int o3 = (tid & 31) * 3;
  int t4 = (tid >> 5) * 4;
  float acc[4][3], accr[4][3];
#pragma unroll
  for (int mt = 0; mt < 4; mt++)
#pragma unroll
    for (int j = 0; j < 3; j++) { acc[mt][j] = 0.f; accr[mt][j] = 0.f; }

  for (int ic = 0; ic < 8; ic++) {
    __syncthreads();
    int i0 = ic * 16;
    for (int idx = tid; idx < 48 * 96; idx += 256) ws2[idx] = w2T[i0 * 3 * 96 + idx];
    for (int idx = tid; idx < 16 * 96; idx += 256) wsr[idx] = wrT[i0 * 96 + idx];
    __syncthreads();
#pragma unroll
    for (int ii = 0; ii < 16; ii++) {
      int i = i0 + ii;
      float a[4][3];
#pragma unroll
      for (int mt = 0; mt < 4; mt++)
#pragma unroll
        for (int k = 0; k < 3; k++)
          a[mt][k] = bf2f(xs2[(4 * (t4 + mt) + k) * 128 + i]);
#pragma unroll
      for (int k = 0; k < 3; k++) {
        float w0 = ws2[(ii * 3 + k) * 96 + o3];
        float w1 = ws2[(ii * 3 + k) * 96 + o3 + 1];
        float w2v = ws2[(ii * 3 + k) * 96 + o3 + 2];
#pragma unroll
        for (int mt = 0; mt < 4; mt++) {
          acc[mt][0] += a[mt][k] * w0;
          acc[mt][1] += a[mt][k] * w1;
          acc[mt][2] += a[mt][k] * w2v;
        }
      }
      float r0 = wsr[ii * 96 + o3];
      float r1 = wsr[ii * 96 + o3 + 1];
      float r2 = wsr[ii * 96 + o3 + 2];
#pragma unroll
      for (int mt = 0; mt < 4; mt++) {
        accr[mt][0] += a[mt][1] * r0;
        accr[mt][1] += a[mt][1] * r1;
        accr[mt][2] += a[mt][1] * r2;
      }
    }
  }
  float A0 = al2[o3], A1 = al2[o3 + 1], A2 = al2[o3 + 2];
  float B0 = be2[o3], B1 = be2[o3 + 1], B2 = be2[o3 + 2];
  float Ar0 = alr[o3], Ar1 = alr[o3 + 1], Ar2 = alr[o3 + 2];
  float Br0 = ber[o3], Br1 = ber[o3 + 1], Br2 = ber[o3 + 2];
  float* sb = seq + ((size_t)b * T2 + t20 + t4) * 96 + o3;
#pragma unroll
  for (int mt = 0; mt < 4; mt++) {
    sb[(size_t)mt * 96 + 0] = fmaxf(acc[mt][0] * A0 + B0, 0.f) + accr[mt][0] * Ar0 + Br0;
    sb[(size_t)mt * 96 + 1] = fmaxf(acc[mt][1] * A1 + B1, 0.f) + accr[mt][1] * Ar1 + Br1;
    sb[(size_t)mt * 96 + 2] = fmaxf(acc[mt][2] * A2 + B2, 0.f) + accr[mt][2] * Ar2 + Br2;
  }
}

// ---------------- K3: pre = seq @ wxT + bias -> [B][1024][384] f32 (permuted: idx = ch*4+g) ----------------
__launch_bounds__(256)
__global__ void k_pre(const float* __restrict__ seq, const float* __restrict__ wxT,
                      const float* __restrict__ bias, float* __restrict__ pre)
{
  __shared__ float seqs[32 * 96];
  __shared__ __align__(16) float wxs[96 * 128];
  int tid = threadIdx.x;
  int b = blockIdx.z, nt = blockIdx.y, t20 = blockIdx.x * 32;
  int g0 = nt * 128;
  for (int idx = tid; idx < 32 * 96; idx += 256)
    seqs[idx] = seq[((size_t)b * T2 + t20) * 96 + idx];
  for (int idx = tid; idx < 96 * 128; idx += 256) {
    int h = idx >> 7, c = idx & 127;
    wxs[idx] = wxT[h * 384 + g0 + c];
  }
  __syncthreads();
  int lane32 = tid & 31, o4 = lane32 * 4, t4 = (tid >> 5) * 4;
  float acc[4][4];
#pragma unroll
  for (int mt = 0; mt < 4; mt++)
#pragma unroll
    for (int j = 0; j < 4; j++) acc[mt][j] = 0.f;
  for (int k = 0; k < 96; k++) {
    float4 bw = ((const float4*)wxs)[k * 32 + lane32];
    float a0 = seqs[(t4 + 0) * 96 + k];
    float a1 = seqs[(t4 + 1) * 96 + k];
    float a2 = seqs[(t4 + 2) * 96 + k];
    float a3 = seqs[(t4 + 3) * 96 + k];
    acc[0][0] += a0 * bw.x; acc[0][1] += a0 * bw.y; acc[0][2] += a0 * bw.z; acc[0][3] += a0 * bw.w;
    acc[1][0] += a1 * bw.x; acc[1][1] += a1 * bw.y; acc[1][2] += a1 * bw.z; acc[1][3] += a1 * bw.w;
    acc[2][0] += a2 * bw.x; acc[2][1] += a2 * bw.y; acc[2][2] += a2 * bw.z; acc[2][3] += a2 * bw.w;
    acc[3][0] += a3 * bw.x; acc[3][1] += a3 * bw.y; acc[3][2] += a3 * bw.z; acc[3][3] += a3 * bw.w;
  }
  float4 b4 = *(const float4*)(bias + g0 + o4);
  float* pb = pre + ((size_t)b * T2 + t20 + t4) * 384 + g0 + o4;
#pragma unroll
  for (int mt = 0; mt < 4; mt++) {
    float4 v;
    v.x = acc[mt][0] + b4.x; v.y = acc[mt][1] + b4.y;
    v.z = acc[mt][2] + b4.z; v.w = acc[mt][3] + b4.w;
    *(float4*)(pb + (size_t)mt * 384) = v;
  }
}

// ---------------- K4: sLSTM recurrence v3 ----------------
// 256 threads = 4 waves (1/SIMD), one block per batch.
// Wave w owns channels [24w, 24w+24). Lane (q=lane>>2, j=lane&3):
//   6 local rows lr=6q..6q+5 (lr = ch_local*4 + gate), 24-wide h-slice j*24.
//   Weights in 144 VGPRs. Quad reduce via DPP quad_perm (VALU pipe, no DS).
//   Preact write->gather is intra-wave (LDS FIFO), gate math in lanes 0..23,
//   one s_barrier per step (h publish, ping-pong hbuf).
// pre is read as [t][ch*4+g] float4 per gate lane, prefetch distance 2.
__launch_bounds__(256, 1)
__global__ void k_slstm(const float* __restrict__ pre, const float* __restrict__ wh,
                        float* __restrict__ hsum)
{
  __shared__ __align__(16) float hbuf[2][96];
  __shared__ __align__(16) float pwbuf[4][96];
  int tid = threadIdx.x;
  int b = blockIdx.x;
  int w = tid >> 6;
  int lane = tid & 63;
  int q = lane >> 2, j = lane & 3;

  // weights: wq[a][kq] = wh[(g*96+ch)*96 + j*24 + kq*4 ...]
  float4 wq[6][6];
#pragma unroll
  for (int a = 0; a < 6; a++) {
    int lr = 6 * q + a;
    int chl = lr >> 2, g = lr & 3;
    int ch = w * 24 + chl;
    const float4* wrow = (const float4*)(wh + ((size_t)(g * 96 + ch)) * 96 + j * 24);
#pragma unroll
    for (int kq = 0; kq < 6; kq++) wq[a][kq] = wrow[kq];
  }

  bool gl = (lane < 24);
  float c = 0.f, n = 0.f, m = 0.f, hs = 0.f;
  if (tid < 96) hbuf[0][tid] = 0.f;
  __syncthreads();

  // px prefetch (gate lanes): float4 (z,i,f,o) for ch = w*24+lane
  const float4* pxp = (const float4*)(pre + (size_t)b * T2 * G4) + (w * 24 + lane);
  float4 pxA = make_float4(0, 0, 0, 0), pxB = pxA;
  if (gl) { pxA = pxp[0]; pxB = pxp[96]; }

  const float L2E = 1.44269504f;
  int p = 0;
  for (int t = 0; t < T2; t++) {
    float4 pxN = make_float4(0, 0, 0, 0);
    if (gl) {
      int tn = t + 2 < T2 ? t + 2 : T2 - 1;
      pxN = pxp[(size_t)tn * 96];
    }
    // h slice (6 x ds_read_b128, 4 distinct addrs/wave, conflict-free)
    float4 hq[6];
#pragma unroll
    for (int kq = 0; kq < 6; kq++) hq[kq] = *(const float4*)(&hbuf[p][j * 24 + kq * 4]);

    float acc[6];
#pragma unroll
    for (int a = 0; a < 6; a++) {
      float s = 0.f;
#pragma unroll
      for (int kq = 0; kq < 6; kq++) {
        s += hq[kq].x * wq[a][kq].x;
        s += hq[kq].y * wq[a][kq].y;
        s += hq[kq].z * wq[a][kq].z;
        s += hq[kq].w * wq[a][kq].w;
      }
      // quad reduce over j (VALU-only DPP)
      s += dpp_xor1(s);
      s += dpp_xor2(s);
      acc[a] = s;
    }
    // intra-wave preact publish (j==0 lanes)
    if (j == 0) {
      *(float2*)(&pwbuf[w][6 * q + 0]) = make_float2(acc[0], acc[1]);
      *(float2*)(&pwbuf[w][6 * q + 2]) = make_float2(acc[2], acc[3]);
      *(float2*)(&pwbuf[w][6 * q + 4]) = make_float2(acc[4], acc[5]);
    }
    asm volatile("" ::: "memory");  // keep DS order (HW: per-wave LDS FIFO)
    if (gl) {
      float4 pa = *(const float4*)(&pwbuf[w][lane * 4]);
      float zp = pa.x + pxA.x, ip = pa.y + pxA.y;
      float fp = pa.z + pxA.z, op = pa.w + pxA.w;
      float zc = fminf(fmaxf(zp, -30.f), 30.f);
      float ez = exp2f(zc * (2.f * L2E));
      float z = 1.f - 2.f * __builtin_amdgcn_rcpf(ez + 1.f);
      float oc = fminf(fmaxf(op, -30.f), 30.f);
      float o = __builtin_amdgcn_rcpf(1.f + exp2f(-oc * L2E));
      float mn = fmaxf(fp + m, ip);
      float iv = exp2f((ip - mn) * L2E);
      float fv = exp2f((fp + m - mn) * L2E);
      c = fv * c + iv * z;
      n = fv * n + iv;
      m = mn;
      float h = o * c * __builtin_amdgcn_rcpf(fmaxf(n, 1.f));
      hs += h;
      hbuf[p ^ 1][w * 24 + lane] = h;
    }
    pxA = pxB; pxB = pxN;
    __syncthreads();
    p ^= 1;
  }
  if (gl) hsum[b * 96 + w * 24 + lane] = hs * (1.f / 1024.f);
}

// ---------------- K5: head: mean-pooled -> fc1+relu -> fc2 ----------------
__launch_bounds__(128)
__global__ void k_head(const float* __restrict__ hsum, const float* __restrict__ fc1w,
                       const float* __restrict__ fc1b, const float* __restrict__ fc2w,
                       const float* __restrict__ fc2b, float* __restrict__ out)
{
  __shared__ float p[96];
  __shared__ float z1[128];
  int tid = threadIdx.x, b = blockIdx.x;
  if (tid < 96) p[tid] = hsum[b * 96 + tid];
  __syncthreads();
  {
    float a = fc1b[tid];
    const float* wr = fc1w + tid * 96;
    for (int h = 0; h < 96; h++) a += p[h] * wr[h];
    z1[tid] = fmaxf(a, 0.f);
  }
  __syncthreads();
  if (tid < NC) {
    float a = fc2b[tid];
    const float* wr = fc2w + tid * 128;
    for (int j = 0; j < 128; j++) a += z1[j] * wr[j];
    out[b * NC + tid] = a;
  }
}

extern "C" void kernel_launch(void* const* d_in, const int* in_sizes, int n_in,
                              void* d_out, int out_size, void* d_ws, size_t ws_size,
                              hipStream_t stream)
{
  const float* x    = (const float*)d_in[0];
  const float* w1   = (const float*)d_in[1];
  const float* cb1  = (const float*)d_in[2];
  const float* g1   = (const float*)d_in[3];
  const float* b1   = (const float*)d_in[4];
  const float* m1   = (const float*)d_in[5];
  const float* v1   = (const float*)d_in[6];
  const float* w2   = (const float*)d_in[7];
  const float* cb2  = (const float*)d_in[8];
  const float* g2   = (const float*)d_in[9];
  const float* b2   = (const float*)d_in[10];
  const float* m2   = (const float*)d_in[11];
  const float* v2   = (const float*)d_in[12];
  const float* wr   = (const float*)d_in[13];
  const float* cbr  = (const float*)d_in[14];
  const float* gr   = (const float*)d_in[15];
  const float* br   = (const float*)d_in[16];
  const float* mr   = (const float*)d_in[17];
  const float* vr   = (const float*)d_in[18];
  const float* wx   = (const float*)d_in[19];
  const float* wh   = (const float*)d_in[20];
  const float* sbia = (const float*)d_in[21];
  const float* fc1w = (const float*)d_in[22];
  const float* fc1b = (const float*)d_in[23];
  const float* fc2w = (const float*)d_in[24];
  const float* fc2b = (const float*)d_in[25];

  char* ws = (char*)d_ws;
  size_t off = 0;
  auto alloc = [&](size_t bytes) -> void* {
    void* p = (void*)(ws + off);
    off = (off + bytes + 255) & ~((size_t)255);
    return p;
  };
  u16*   out1 = (u16*)  alloc((size_t)Bz * Tt * K1c * 2);   // 67.1 MB
  float* seq  = (float*)alloc((size_t)Bz * T2 * Hh * 4);    // 25.2 MB
  float* pre  = (float*)alloc((size_t)Bz * T2 * G4 * 4);    // 100.7 MB
  u16*   w1b  = (u16*)  alloc(448 * 128 * 2);
  float* w2T  = (float*)alloc(384 * 96 * 4);
  float* wrT  = (float*)alloc(128 * 96 * 4);
  float* wxT  = (float*)alloc(96 * 384 * 4);
  float* bperm= (float*)alloc(384 * 4);
  float* al1  = (float*)alloc(128 * 4);
  float* be1  = (float*)alloc(128 * 4);
  float* al2  = (float*)alloc(96 * 4);
  float* be2  = (float*)alloc(96 * 4);
  float* alr  = (float*)alloc(96 * 4);
  float* ber  = (float*)alloc(96 * 4);
  float* hsum = (float*)alloc((size_t)Bz * Hh * 4);
  (void)ws_size; (void)in_sizes; (void)n_in; (void)out_size;

  k_prep<<<dim3(224), dim3(256), 0, stream>>>(
      w1, cb1, g1, b1, m1, v1, w2, cb2, g2, b2, m2, v2,
      wr, cbr, gr, br, mr, vr, wx, sbia,
      w1b, w2T, wrT, wxT, bperm, al1, be1, al2, be2, alr, ber);

  k_conv1<<<dim3(Tt / 128, Bz), dim3(256), 0, stream>>>(x, w1b, al1, be1, out1);

  k_conv2<<<dim3(T2 / 32, Bz), dim3(256), 0, stream>>>(out1, w2T, wrT, al2, be2, alr, ber, seq);

  k_pre<<<dim3(T2 / 32, 3, Bz), dim3(256), 0, stream>>>(seq, wxT, bperm, pre);

  k_slstm<<<dim3(Bz), dim3(256), 0, stream>>>(pre, wh, hsum);

  k_head<<<dim3(Bz), dim3(128), 0, stream>>>(hsum, fc1w, fc1b, fc2w, fc2b, (float*)d_out);
}

// Round 5
// 794.202 us; speedup vs baseline: 2.3431x; 1.2695x over previous
//
#include <hip/hip_runtime.h>
#include <hip/hip_bf16.h>
#include <math.h>

typedef unsigned short u16;
typedef short bf16x8 __attribute__((ext_vector_type(8)));
typedef float f32x4 __attribute__((ext_vector_type(4)));

#define Bz 64
#define Tt 4096
#define Cin 64
#define K1c 128
#define Hh 96
#define T2 1024
#define G4 384
#define NC 109

#define MFMA16(a, b, c) __builtin_amdgcn_mfma_f32_16x16x32_bf16(a, b, c, 0, 0, 0)

__device__ __forceinline__ float bf2f(u16 v) {
  union { unsigned int u; float f; } x; x.u = ((unsigned int)v) << 16; return x.f;
}
__device__ __forceinline__ u16 f2bf(float f) {
  union { unsigned int u; float f; } x; x.f = f;
  unsigned int u = x.u;
  unsigned int r = u + 0x7fff + ((u >> 16) & 1);
  return (u16)(r >> 16);
}
__device__ __forceinline__ float dpp_xor1(float x) {
  int r = __builtin_amdgcn_mov_dpp(__float_as_int(x), 0xB1, 0xF, 0xF, true);
  return __int_as_float(r);
}
__device__ __forceinline__ float dpp_xor2(float x) {
  int r = __builtin_amdgcn_mov_dpp(__float_as_int(x), 0x4E, 0xF, 0xF, true);
  return __int_as_float(r);
}

// ---------------- K0: weight packing + BN folding ----------------
__global__ void k_prep(const float* __restrict__ w1, const float* __restrict__ cb1,
                       const float* __restrict__ g1, const float* __restrict__ b1,
                       const float* __restrict__ m1, const float* __restrict__ v1,
                       const float* __restrict__ w2, const float* __restrict__ cb2,
                       const float* __restrict__ g2, const float* __restrict__ b2,
                       const float* __restrict__ m2, const float* __restrict__ v2,
                       const float* __restrict__ wr, const float* __restrict__ cbr,
                       const float* __restrict__ gr, const float* __restrict__ br,
                       const float* __restrict__ mr, const float* __restrict__ vr,
                       const float* __restrict__ wx, const float* __restrict__ sbia,
                       u16* __restrict__ w1b, u16* __restrict__ w2b,
                       u16* __restrict__ wrb, float* __restrict__ wxT,
                       float* __restrict__ bperm,
                       float* __restrict__ al1, float* __restrict__ be1,
                       float* __restrict__ al2, float* __restrict__ be2,
                       float* __restrict__ alr, float* __restrict__ ber)
{
  int tid = blockIdx.x * blockDim.x + threadIdx.x;
  int nth = gridDim.x * blockDim.x;
  // w1b[o*448 + kt*64 + c] = bf16(w1[o][c][kt])
  for (int idx = tid; idx < 128 * 448; idx += nth) {
    int o = idx / 448, k = idx % 448;
    int kt = k >> 6, c = k & 63;
    w1b[idx] = f2bf(w1[(o * 64 + c) * 7 + kt]);
  }
  // w2b[o*384 + kk*128 + c] = bf16(w2[o][c][kk])
  for (int idx = tid; idx < 96 * 384; idx += nth) {
    int o = idx / 384, k = idx % 384;
    int kk = k >> 7, c = k & 127;
    w2b[idx] = f2bf(w2[(o * 128 + c) * 3 + kk]);
  }
  // wrb[o*128 + c] = bf16(wr[o][c])
  for (int idx = tid; idx < 96 * 128; idx += nth) {
    wrb[idx] = f2bf(wr[idx]);
  }
  // wxT[h*384 + (ch*4+g)] = wx[g*96+ch][h]  (permuted: ch-major gate packing)
  for (int idx = tid; idx < 96 * 384; idx += nth) {
    int c = idx % 384, h = idx / 384;
    int ch = c >> 2, g = c & 3;
    wxT[idx] = wx[((size_t)(g * 96 + ch)) * 96 + h];
  }
  // bperm[ch*4+g] = sbia[g*96+ch]
  for (int c = tid; c < 384; c += nth) {
    int ch = c >> 2, g = c & 3;
    bperm[c] = sbia[g * 96 + ch];
  }
  for (int o = tid; o < 128; o += nth) {
    float a = g1[o] / sqrtf(v1[o] + 1e-5f);
    al1[o] = a; be1[o] = b1[o] + (cb1[o] - m1[o]) * a;
  }
  for (int o = tid; o < 96; o += nth) {
    float a = g2[o] / sqrtf(v2[o] + 1e-5f);
    al2[o] = a; be2[o] = b2[o] + (cb2[o] - m2[o]) * a;
    float ar = gr[o] / sqrtf(vr[o] + 1e-5f);
    alr[o] = ar; ber[o] = br[o] + (cbr[o] - mr[o]) * ar;
  }
}

// ---------------- K1: conv1 MFMA implicit GEMM (unchanged from R4) ----------------
__launch_bounds__(256, 2)
__global__ void k_conv1(const float* __restrict__ x, const u16* __restrict__ w1b,
                        const float* __restrict__ al1, const float* __restrict__ be1,
                        u16* __restrict__ out1)
{
  __shared__ __align__(16) u16 xs[134 * 72];
  int tid = threadIdx.x;
  int b = blockIdx.y;
  int t0 = blockIdx.x * 128;
  const float* xb = x + (size_t)b * Tt * Cin;

  for (int idx = tid; idx < 134 * 16; idx += 256) {
    int row = idx >> 4, c4 = (idx & 15) << 2;
    int gt = t0 - 3 + row;
    float4 v = make_float4(0.f, 0.f, 0.f, 0.f);
    if (gt >= 0 && gt < Tt) v = *(const float4*)(xb + (size_t)gt * 64 + c4);
    ushort4 s;
    s.x = f2bf(v.x); s.y = f2bf(v.y); s.z = f2bf(v.z); s.w = f2bf(v.w);
    *(ushort4*)(xs + row * 72 + c4) = s;
  }
  __syncthreads();

  int l = tid & 63;
  int wid = tid >> 6;
  int wm = wid >> 1, wn = wid & 1;
  int lr = l & 15, g = l >> 4;

  f32x4 acc[4][4];
#pragma unroll
  for (int i = 0; i < 4; i++)
#pragma unroll
    for (int j = 0; j < 4; j++) acc[i][j] = (f32x4){0.f, 0.f, 0.f, 0.f};

  const u16* wbase = w1b + (size_t)(wn * 64 + lr) * 448;

  for (int s = 0; s < 14; ++s) {
    int kt = s >> 1;
    int cofs = ((s & 1) << 5) + (g << 3);
    const u16* xrow = xs + (wm * 64 + lr + kt) * 72 + cofs;
    bf16x8 a0 = *(const bf16x8*)(xrow);
    bf16x8 a1 = *(const bf16x8*)(xrow + 16 * 72);
    bf16x8 a2 = *(const bf16x8*)(xrow + 32 * 72);
    bf16x8 a3 = *(const bf16x8*)(xrow + 48 * 72);
    int ko = (s << 5) + (g << 3);
    bf16x8 b0 = *(const bf16x8*)(wbase + ko);
    bf16x8 b1 = *(const bf16x8*)(wbase + 16 * 448 + ko);
    bf16x8 b2 = *(const bf16x8*)(wbase + 32 * 448 + ko);
    bf16x8 b3 = *(const bf16x8*)(wbase + 48 * 448 + ko);
    acc[0][0] = MFMA16(a0, b0, acc[0][0]);
    acc[0][1] = MFMA16(a0, b1, acc[0][1]);
    acc[0][2] = MFMA16(a0, b2, acc[0][2]);
    acc[0][3] = MFMA16(a0, b3, acc[0][3]);
    acc[1][0] = MFMA16(a1, b0, acc[1][0]);
    acc[1][1] = MFMA16(a1, b1, acc[1][1]);
    acc[1][2] = MFMA16(a1, b2, acc[1][2]);
    acc[1][3] = MFMA16(a1, b3, acc[1][3]);
    acc[2][0] = MFMA16(a2, b0, acc[2][0]);
    acc[2][1] = MFMA16(a2, b1, acc[2][1]);
    acc[2][2] = MFMA16(a2, b2, acc[2][2]);
    acc[2][3] = MFMA16(a2, b3, acc[2][3]);
    acc[3][0] = MFMA16(a3, b0, acc[3][0]);
    acc[3][1] = MFMA16(a3, b1, acc[3][1]);
    acc[3][2] = MFMA16(a3, b2, acc[3][2]);
    acc[3][3] = MFMA16(a3, b3, acc[3][3]);
  }

  int colb = wn * 64 + lr;
  int rowb = t0 + wm * 64 + (l >> 4) * 4;
#pragma unroll
  for (int nf = 0; nf < 4; nf++) {
    int col = colb + nf * 16;
    float A = al1[col], Bt = be1[col];
#pragma unroll
    for (int mf = 0; mf < 4; mf++) {
      int row = rowb + mf * 16;
#pragma unroll
      for (int r = 0; r < 4; r++) {
        float v = acc[mf][nf][r];
        v = fmaxf(v * A + Bt, 0.f);
        out1[((size_t)b * Tt + row + r) * 128 + col] = f2bf(v);
      }
    }
  }
}

// ---------------- K2: conv2 MFMA implicit GEMM + fused residual ----------------
// M = B*T2 (tile 64 rows), N = 96 (2x48), K = 384 (kk*128+c). Residual (K=128,
// kk=1 tap) folded: reuses kk=1 A-frags with res weights. No LDS, no barriers.
__launch_bounds__(256, 4)
__global__ void k_conv2(const u16* __restrict__ out1, const u16* __restrict__ w2b,
                        const u16* __restrict__ wrb,
                        const float* __restrict__ al2, const float* __restrict__ be2,
                        const float* __restrict__ alr, const float* __restrict__ ber,
                        float* __restrict__ seq)
{
  int tid = threadIdx.x;
  int b = blockIdx.y;
  int t20 = blockIdx.x * 64;
  int l = tid & 63;
  int wid = tid >> 6;
  int wm = wid >> 1, wn = wid & 1;    // wave tile 32 x 48
  int lr = l & 15, g = l >> 4;

  f32x4 acc[2][3], accr[2][3];
#pragma unroll
  for (int i = 0; i < 2; i++)
#pragma unroll
    for (int j = 0; j < 3; j++) {
      acc[i][j] = (f32x4){0.f, 0.f, 0.f, 0.f};
      accr[i][j] = (f32x4){0.f, 0.f, 0.f, 0.f};
    }

  const u16* ob = out1 + (size_t)b * Tt * 128;
  int colb = wn * 48 + lr;

#pragma unroll
  for (int f = 0; f < 12; f++) {
    int kk = f >> 2;
    int c = ((f & 3) << 5) + (g << 3);
    bf16x8 a[2];
#pragma unroll
    for (int mf = 0; mf < 2; mf++) {
      int t2 = t20 + wm * 32 + mf * 16 + lr;
      int gt = 4 * t2 + kk - 1;
      if (gt >= 0)
        a[mf] = *(const bf16x8*)(ob + (size_t)gt * 128 + c);
      else
        a[mf] = (bf16x8){0, 0, 0, 0, 0, 0, 0, 0};
    }
#pragma unroll
    for (int nf = 0; nf < 3; nf++) {
      int col = colb + nf * 16;
      bf16x8 bb = *(const bf16x8*)(w2b + (size_t)col * 384 + (f << 5) + (g << 3));
      acc[0][nf] = MFMA16(a[0], bb, acc[0][nf]);
      acc[1][nf] = MFMA16(a[1], bb, acc[1][nf]);
    }
    if (kk == 1) {
#pragma unroll
      for (int nf = 0; nf < 3; nf++) {
        int col = colb + nf * 16;
        bf16x8 br = *(const bf16x8*)(wrb + (size_t)col * 128 + ((f & 3) << 5) + (g << 3));
        accr[0][nf] = MFMA16(a[0], br, accr[0][nf]);
        accr[1][nf] = MFMA16(a[1], br, accr[1][nf]);
      }
    }
  }

  // epilogue: seq = relu(acc*al2+be2) + accr*alr+ber
  int rowb = t20 + wm * 32 + (l >> 4) * 4;
#pragma unroll
  for (int nf = 0; nf < 3; nf++) {
    int col = colb + nf * 16;
    float A = al2[col], Bt = be2[col];
    float Ar = alr[col], Br = ber[col];
#pragma unroll
    for (int mf = 0; mf < 2; mf++) {
      int row = rowb + mf * 16;
#pragma unroll
      for (int r = 0; r < 4; r++) {
        float v = fmaxf(acc[mf][nf][r] * A + Bt, 0.f) + accr[mf][nf][r] * Ar + Br;
        seq[((size_t)b * T2 + row + r) * 96 + col] = v;
      }
    }
  }
}

// ---------------- K3: pre = seq @ wxT + bias, fp32, zero-LDS ----------------
// Block: 128 t-rows x 128 cols. Thread: 16 rows x 4 cols. A-loads are
// wave-uniform broadcasts (L1-resident), B coalesced from L2. FMA-bound.
__launch_bounds__(256)
__global__ void k_pre(const float* __restrict__ seq, const float* __restrict__ wxT,
                      const float* __restrict__ bias, float* __restrict__ pre)
{
  int tid = threadIdx.x;
  int b = blockIdx.z, nt = blockIdx.y, t20 = blockIdx.x * 128;
  int g0 = nt * 128;
  int lane32 = tid & 31, col4 = lane32 * 4;
  int trow = (tid >> 5) * 16;

  const float* sb = seq + ((size_t)b * T2 + t20 + trow) * 96;
  const float* wb = wxT + g0 + col4;

  f32x4 acc[16];
#pragma unroll
  for (int r = 0; r < 16; r++) acc[r] = (f32x4){0.f, 0.f, 0.f, 0.f};

  for (int kb = 0; kb < 96; kb += 4) {
    f32x4 bw0 = *(const f32x4*)(wb + (size_t)(kb + 0) * 384);
    f32x4 bw1 = *(const f32x4*)(wb + (size_t)(kb + 1) * 384);
    f32x4 bw2 = *(const f32x4*)(wb + (size_t)(kb + 2) * 384);
    f32x4 bw3 = *(const f32x4*)(wb + (size_t)(kb + 3) * 384);
#pragma unroll
    for (int r = 0; r < 16; r++) {
      f32x4 av = *(const f32x4*)(sb + (size_t)r * 96 + kb);
      acc[r] += av.x * bw0;
      acc[r] += av.y * bw1;
      acc[r] += av.z * bw2;
      acc[r] += av.w * bw3;
    }
  }

  f32x4 b4 = *(const f32x4*)(bias + g0 + col4);
  float* pb = pre + ((size_t)b * T2 + t20 + trow) * 384 + g0 + col4;
#pragma unroll
  for (int r = 0; r < 16; r++) {
    *(f32x4*)(pb + (size_t)r * 384) = acc[r] + b4;
  }
}

// ---------------- K4: sLSTM recurrence v3 (unchanged) ----------------
__launch_bounds__(256, 1)
__global__ void k_slstm(const float* __restrict__ pre, const float* __restrict__ wh,
                        float* __restrict__ hsum)
{
  __shared__ __align__(16) float hbuf[2][96];
  __shared__ __align__(16) float pwbuf[4][96];
  int tid = threadIdx.x;
  int b = blockIdx.x;
  int w = tid >> 6;
  int lane = tid & 63;
  int q = lane >> 2, j = lane & 3;

  float4 wq[6][6];
#pragma unroll
  for (int a = 0; a < 6; a++) {
    int lr = 6 * q + a;
    int chl = lr >> 2, g = lr & 3;
    int ch = w * 24 + chl;
    const float4* wrow = (const float4*)(wh + ((size_t)(g * 96 + ch)) * 96 + j * 24);
#pragma unroll
    for (int kq = 0; kq < 6; kq++) wq[a][kq] = wrow[kq];
  }

  bool gl = (lane < 24);
  float c = 0.f, n = 0.f, m = 0.f, hs = 0.f;
  if (tid < 96) hbuf[0][tid] = 0.f;
  __syncthreads();

  const float4* pxp = (const float4*)(pre + (size_t)b * T2 * G4) + (w * 24 + lane);
  float4 pxA = make_float4(0, 0, 0, 0), pxB = pxA;
  if (gl) { pxA = pxp[0]; pxB = pxp[96]; }

  const float L2E = 1.44269504f;
  int p = 0;
  for (int t = 0; t < T2; t++) {
    float4 pxN = make_float4(0, 0, 0, 0);
    if (gl) {
      int tn = t + 2 < T2 ? t + 2 : T2 - 1;
      pxN = pxp[(size_t)tn * 96];
    }
    float4 hq[6];
#pragma unroll
    for (int kq = 0; kq < 6; kq++) hq[kq] = *(const float4*)(&hbuf[p][j * 24 + kq * 4]);

    float acc[6];
#pragma unroll
    for (int a = 0; a < 6; a++) {
      float s = 0.f;
#pragma unroll
      for (int kq = 0; kq < 6; kq++) {
        s += hq[kq].x * wq[a][kq].x;
        s += hq[kq].y * wq[a][kq].y;
        s += hq[kq].z * wq[a][kq].z;
        s += hq[kq].w * wq[a][kq].w;
      }
      s += dpp_xor1(s);
      s += dpp_xor2(s);
      acc[a] = s;
    }
    if (j == 0) {
      *(float2*)(&pwbuf[w][6 * q + 0]) = make_float2(acc[0], acc[1]);
      *(float2*)(&pwbuf[w][6 * q + 2]) = make_float2(acc[2], acc[3]);
      *(float2*)(&pwbuf[w][6 * q + 4]) = make_float2(acc[4], acc[5]);
    }
    asm volatile("" ::: "memory");
    if (gl) {
      float4 pa = *(const float4*)(&pwbuf[w][lane * 4]);
      float zp = pa.x + pxA.x, ip = pa.y + pxA.y;
      float fp = pa.z + pxA.z, op = pa.w + pxA.w;
      float zc = fminf(fmaxf(zp, -30.f), 30.f);
      float ez = exp2f(zc * (2.f * L2E));
      float z = 1.f - 2.f * __builtin_amdgcn_rcpf(ez + 1.f);
      float oc = fminf(fmaxf(op, -30.f), 30.f);
      float o = __builtin_amdgcn_rcpf(1.f + exp2f(-oc * L2E));
      float mn = fmaxf(fp + m, ip);
      float iv = exp2f((ip - mn) * L2E);
      float fv = exp2f((fp + m - mn) * L2E);
      c = fv * c + iv * z;
      n = fv * n + iv;
      m = mn;
      float h = o * c * __builtin_amdgcn_rcpf(fmaxf(n, 1.f));
      hs += h;
      hbuf[p ^ 1][w * 24 + lane] = h;
    }
    pxA = pxB; pxB = pxN;
    __syncthreads();
    p ^= 1;
  }
  if (gl) hsum[b * 96 + w * 24 + lane] = hs * (1.f / 1024.f);
}

// ---------------- K5: head (unchanged) ----------------
__launch_bounds__(128)
__global__ void k_head(const float* __restrict__ hsum, const float* __restrict__ fc1w,
                       const float* __restrict__ fc1b, const float* __restrict__ fc2w,
                       const float* __restrict__ fc2b, float* __restrict__ out)
{
  __shared__ float p[96];
  __shared__ float z1[128];
  int tid = threadIdx.x, b = blockIdx.x;
  if (tid < 96) p[tid] = hsum[b * 96 + tid];
  __syncthreads();
  {
    float a = fc1b[tid];
    const float* wr = fc1w + tid * 96;
    for (int h = 0; h < 96; h++) a += p[h] * wr[h];
    z1[tid] = fmaxf(a, 0.f);
  }
  __syncthreads();
  if (tid < NC) {
    float a = fc2b[tid];
    const float* wr = fc2w + tid * 128;
    for (int j = 0; j < 128; j++) a += z1[j] * wr[j];
    out[b * NC + tid] = a;
  }
}

extern "C" void kernel_launch(void* const* d_in, const int* in_sizes, int n_in,
                              void* d_out, int out_size, void* d_ws, size_t ws_size,
                              hipStream_t stream)
{
  const float* x    = (const float*)d_in[0];
  const float* w1   = (const float*)d_in[1];
  const float* cb1  = (const float*)d_in[2];
  const float* g1   = (const float*)d_in[3];
  const float* b1   = (const float*)d_in[4];
  const float* m1   = (const float*)d_in[5];
  const float* v1   = (const float*)d_in[6];
  const float* w2   = (const float*)d_in[7];
  const float* cb2  = (const float*)d_in[8];
  const float* g2   = (const float*)d_in[9];
  const float* b2   = (const float*)d_in[10];
  const float* m2   = (const float*)d_in[11];
  const float* v2   = (const float*)d_in[12];
  const float* wr   = (const float*)d_in[13];
  const float* cbr  = (const float*)d_in[14];
  const float* gr   = (const float*)d_in[15];
  const float* br   = (const float*)d_in[16];
  const float* mr   = (const float*)d_in[17];
  const float* vr   = (const float*)d_in[18];
  const float* wx   = (const float*)d_in[19];
  const float* wh   = (const float*)d_in[20];
  const float* sbia = (const float*)d_in[21];
  const float* fc1w = (const float*)d_in[22];
  const float* fc1b = (const float*)d_in[23];
  const float* fc2w = (const float*)d_in[24];
  const float* fc2b = (const float*)d_in[25];

  char* ws = (char*)d_ws;
  size_t off = 0;
  auto alloc = [&](size_t bytes) -> void* {
    void* p = (void*)(ws + off);
    off = (off + bytes + 255) & ~((size_t)255);
    return p;
  };
  u16*   out1 = (u16*)  alloc((size_t)Bz * Tt * K1c * 2);   // 67.1 MB
  float* seq  = (float*)alloc((size_t)Bz * T2 * Hh * 4);    // 25.2 MB
  float* pre  = (float*)alloc((size_t)Bz * T2 * G4 * 4);    // 100.7 MB
  u16*   w1b  = (u16*)  alloc(448 * 128 * 2);
  u16*   w2b  = (u16*)  alloc(96 * 384 * 2);
  u16*   wrb  = (u16*)  alloc(96 * 128 * 2);
  float* wxT  = (float*)alloc(96 * 384 * 4);
  float* bperm= (float*)alloc(384 * 4);
  float* al1  = (float*)alloc(128 * 4);
  float* be1  = (float*)alloc(128 * 4);
  float* al2  = (float*)alloc(96 * 4);
  float* be2  = (float*)alloc(96 * 4);
  float* alr  = (float*)alloc(96 * 4);
  float* ber  = (float*)alloc(96 * 4);
  float* hsum = (float*)alloc((size_t)Bz * Hh * 4);
  (void)ws_size; (void)in_sizes; (void)n_in; (void)out_size;

  k_prep<<<dim3(224), dim3(256), 0, stream>>>(
      w1, cb1, g1, b1, m1, v1, w2, cb2, g2, b2, m2, v2,
      wr, cbr, gr, br, mr, vr, wx, sbia,
      w1b, w2b, wrb, wxT, bperm, al1, be1, al2, be2, alr, ber);

  k_conv1<<<dim3(Tt / 128, Bz), dim3(256), 0, stream>>>(x, w1b, al1, be1, out1);

  k_conv2<<<dim3(T2 / 64, Bz), dim3(256), 0, stream>>>(out1, w2b, wrb, al2, be2, alr, ber, seq);

  k_pre<<<dim3(T2 / 128, 3, Bz), dim3(256), 0, stream>>>(seq, wxT, bperm, pre);

  k_slstm<<<dim3(Bz), dim3(256), 0, stream>>>(pre, wh, hsum);

  k_head<<<dim3(Bz), dim3(128), 0, stream>>>(hsum, fc1w, fc1b, fc2w, fc2b, (float*)d_out);
}